// Round 3
// baseline (26.075 us; speedup 1.0000x reference)
//
#include <hip/hip_runtime.h>

#define TS 68        // tile row stride in floats: 68*4=272 B = 17*16 (rows 16B-aligned), r*68 % 32 -> 2-way alias only (free)
#define TROWS 66     // 64 image rows + 2 halo rows

// One block per image, 256 threads. Image row r -> tile row r+1.
// Image col c -> tile col c+4; halo cols 3 and 68? (right halo at col 68 doesn't exist with TS=68)
// Columns: halo-left at 3, interior 4..67, halo-right would be 68 -> out of TS=68.
// So use TS=72 instead: halo-left 3, interior 4..67, halo-right 68, stride 72 floats = 288 B = 18*16 (16B-aligned rows).
#undef TS
#define TS 72

__global__ __launch_bounds__(256) void sobel_fused_v2(
    const float* __restrict__ in,      // (2048,1,64,64)
    const float* __restrict__ weight,  // (1,9)
    const float* __restrict__ wfac_p,  // (1,)
    const float* __restrict__ scale_p, // (1,1)
    float* __restrict__ out)
{
    __shared__ __align__(16) float tile[TROWS][TS];   // 66*72*4 = 19008 B
    __shared__ float smin[4], smax[4];

    const int tid = threadIdx.x;
    const int img = blockIdx.x;
    const float* __restrict__ src = in + (size_t)img * 4096;
    float* __restrict__ dst = out + (size_t)img * 4096;

    // Build 3x3 kernel: wr = clip(weight,-1,1) * clip(wfac,1,255)
    const float wf = fminf(fmaxf(wfac_p[0], 1.0f), 255.0f);
    float wr[9];
#pragma unroll
    for (int i = 0; i < 9; ++i)
        wr[i] = fminf(fmaxf(weight[i], -1.0f), 1.0f) * wf;
    const float invscale = 1.0f / scale_p[0];

    // Zero halo: top/bottom rows, left/right columns.
    for (int i = tid; i < TS; i += 256) {
        tile[0][i] = 0.0f;
        tile[TROWS - 1][i] = 0.0f;
    }
    if (tid < 64) {
        tile[tid + 1][3]  = 0.0f;
        tile[tid + 1][68] = 0.0f;
    }

    // Stage interior, float4-coalesced: 1024 float4, 4 per thread.
    const float4* __restrict__ src4 = (const float4*)src;
#pragma unroll
    for (int i = 0; i < 4; ++i) {
        int idx = tid + i * 256;        // 0..1023
        int row = idx >> 4;             // 16 float4 per image row
        int c4  = idx & 15;
        *(float4*)&tile[row + 1][4 + c4 * 4] = src4[idx];
    }
    __syncthreads();

    // Each thread: 16 contiguous pixels of image row r, cols cb..cb+15.
    const int r  = tid >> 2;            // 0..63
    const int cb = (tid & 3) << 4;      // 0,16,32,48

    float gx[16], gy[16];
#pragma unroll
    for (int c = 0; c < 16; ++c) { gx[c] = 0.0f; gy[c] = 0.0f; }

#pragma unroll
    for (int dr = 0; dr < 3; ++dr) {
        const float* rowp = &tile[r + dr][0];
        float a[18];                    // tile cols 3+cb .. 20+cb
        a[0] = rowp[3 + cb];
        const float4* r4 = (const float4*)rowp;
#pragma unroll
        for (int j = 0; j < 4; ++j) {
            float4 m = r4[1 + (cb >> 2) + j];   // floats 4+cb+4j .. 7+cb+4j
            a[1 + 4 * j] = m.x; a[2 + 4 * j] = m.y;
            a[3 + 4 * j] = m.z; a[4 + 4 * j] = m.w;
        }
        a[17] = rowp[20 + cb];
        const float wx0 = wr[dr * 3], wx1 = wr[dr * 3 + 1], wx2 = wr[dr * 3 + 2];
        const float wy0 = wr[dr],     wy1 = wr[3 + dr],     wy2 = wr[6 + dr];
#pragma unroll
        for (int c = 0; c < 16; ++c) {
            gx[c] = fmaf(a[c], wx0, fmaf(a[c + 1], wx1, fmaf(a[c + 2], wx2, gx[c])));
            gy[c] = fmaf(a[c], wy0, fmaf(a[c + 1], wy1, fmaf(a[c + 2], wy2, gy[c])));
        }
    }

    float g[16];
    float gmn = __builtin_inff(), gmx = -__builtin_inff();
#pragma unroll
    for (int c = 0; c < 16; ++c) {
        g[c] = fabsf(gx[c]) + fabsf(gy[c]);
        gmn = fminf(gmn, g[c]);
        gmx = fmaxf(gmx, g[c]);
    }

    // 64-lane butterfly, then cross-wave via LDS (R0-proven pattern).
#pragma unroll
    for (int off = 32; off > 0; off >>= 1) {
        gmn = fminf(gmn, __shfl_xor(gmn, off));
        gmx = fmaxf(gmx, __shfl_xor(gmx, off));
    }
    if ((tid & 63) == 0) { smin[tid >> 6] = gmn; smax[tid >> 6] = gmx; }
    __syncthreads();
    gmn = fminf(fminf(smin[0], smin[1]), fminf(smin[2], smin[3]));
    gmx = fmaxf(fmaxf(smax[0], smax[1]), fmaxf(smax[2], smax[3]));

    const float inv = 255.0f / fmaxf(gmx - gmn, 1.0f);

#pragma unroll
    for (int j = 0; j < 4; ++j) {
        float4 o;
        o.x = floorf((g[4 * j]     - gmn) * inv) * invscale;
        o.y = floorf((g[4 * j + 1] - gmn) * inv) * invscale;
        o.z = floorf((g[4 * j + 2] - gmn) * inv) * invscale;
        o.w = floorf((g[4 * j + 3] - gmn) * inv) * invscale;
        *(float4*)&dst[r * 64 + cb + 4 * j] = o;
    }
}

extern "C" void kernel_launch(void* const* d_in, const int* in_sizes, int n_in,
                              void* d_out, int out_size, void* d_ws, size_t ws_size,
                              hipStream_t stream) {
    const float* inp   = (const float*)d_in[0];
    const float* wgt   = (const float*)d_in[1];
    const float* wfac  = (const float*)d_in[2];
    const float* scale = (const float*)d_in[3];
    float* out = (float*)d_out;

    sobel_fused_v2<<<2048, 256, 0, stream>>>(inp, wgt, wfac, scale, out);
}

// Round 4
// 17.808 us; speedup vs baseline: 1.4643x; 1.4643x over previous
//
#include <hip/hip_runtime.h>

// One block per 64x64 image, 256 threads.
// Thread (R = tid>>4, c = tid&15) computes output rows 4R..4R+3, cols 4c..4c+3,
// reading its 6x6 input patch DIRECTLY from global (image = 16 KB, fits L1).
// No LDS staging, no stage barriers -> load/compute/store phases overlap
// across waves instead of serializing chip-wide.
__global__ __launch_bounds__(256) void sobel_direct(
    const float* __restrict__ in,      // (2048,1,64,64)
    const float* __restrict__ weight,  // (1,9)
    const float* __restrict__ wfac_p,  // (1,)
    const float* __restrict__ scale_p, // (1,1)
    float* __restrict__ out)
{
    __shared__ float smin[4], smax[4];

    const int tid = threadIdx.x;
    const int img = blockIdx.x;
    const float* __restrict__ src = in + (size_t)img * 4096;
    float* __restrict__ dst = out + (size_t)img * 4096;

    // wr = clip(weight,-1,1) * clip(wfac,1,255)
    const float wf = fminf(fmaxf(wfac_p[0], 1.0f), 255.0f);
    float wr[9];
#pragma unroll
    for (int i = 0; i < 9; ++i)
        wr[i] = fminf(fmaxf(weight[i], -1.0f), 1.0f) * wf;
    const float invscale = 1.0f / scale_p[0];

    const int c = tid & 15;   // col block: image cols 4c..4c+3
    const int R = tid >> 4;   // row block: image rows 4R..4R+3

    // Load 6x6 window: image rows 4R-1..4R+4, cols 4c-1..4c+4.
    // Aligned float4 (own 4 cols) + 2 predicated scalar neighbors per row.
    float w6[6][6];
#pragma unroll
    for (int k = 0; k < 6; ++k) {
        const int rr = 4 * R - 1 + k;
        const int rrc = min(max(rr, 0), 63);       // clamped (value masked below)
        const float* rowp = src + rrc * 64 + 4 * c;
        const float4 m = *(const float4*)rowp;
        const float lft = (c > 0)  ? rowp[-1] : 0.0f;   // predicated: no OOB when c==0
        const float rgt = (c < 15) ? rowp[4]  : 0.0f;   // predicated: no OOB when c==15
        const bool rv = (rr >= 0) && (rr < 64);
        w6[k][0] = rv ? lft : 0.0f;
        w6[k][1] = rv ? m.x : 0.0f;
        w6[k][2] = rv ? m.y : 0.0f;
        w6[k][3] = rv ? m.z : 0.0f;
        w6[k][4] = rv ? m.w : 0.0f;
        w6[k][5] = rv ? rgt : 0.0f;
    }

    // 3x3 cross-correlation (XLA conv, no flip) with wr and wr^T, |gx|+|gy|.
    float g[4][4];
    float gmn = __builtin_inff(), gmx = -__builtin_inff();
#pragma unroll
    for (int i = 0; i < 4; ++i) {
#pragma unroll
        for (int j = 0; j < 4; ++j) {
            float gx = 0.0f, gy = 0.0f;
#pragma unroll
            for (int dr = 0; dr < 3; ++dr) {
#pragma unroll
                for (int dc = 0; dc < 3; ++dc) {
                    const float a = w6[i + dr][j + dc];
                    gx = fmaf(a, wr[dr * 3 + dc], gx);
                    gy = fmaf(a, wr[dc * 3 + dr], gy);   // transposed kernel
                }
            }
            const float gv = fabsf(gx) + fabsf(gy);
            g[i][j] = gv;
            gmn = fminf(gmn, gv);
            gmx = fmaxf(gmx, gv);
        }
    }

    // Per-image min/max: 64-lane butterfly, then 4 waves via LDS.
#pragma unroll
    for (int off = 32; off > 0; off >>= 1) {
        gmn = fminf(gmn, __shfl_xor(gmn, off));
        gmx = fmaxf(gmx, __shfl_xor(gmx, off));
    }
    if ((tid & 63) == 0) { smin[tid >> 6] = gmn; smax[tid >> 6] = gmx; }
    __syncthreads();
    gmn = fminf(fminf(smin[0], smin[1]), fminf(smin[2], smin[3]));
    gmx = fmaxf(fmaxf(smax[0], smax[1]), fmaxf(smax[2], smax[3]));

    const float inv = 255.0f / fmaxf(gmx - gmn, 1.0f);

    // Store: 4 x float4 per thread, dense 4KB per wave instruction group.
#pragma unroll
    for (int i = 0; i < 4; ++i) {
        float4 o;
        o.x = floorf((g[i][0] - gmn) * inv) * invscale;
        o.y = floorf((g[i][1] - gmn) * inv) * invscale;
        o.z = floorf((g[i][2] - gmn) * inv) * invscale;
        o.w = floorf((g[i][3] - gmn) * inv) * invscale;
        *(float4*)&dst[(4 * R + i) * 64 + 4 * c] = o;
    }
}

extern "C" void kernel_launch(void* const* d_in, const int* in_sizes, int n_in,
                              void* d_out, int out_size, void* d_ws, size_t ws_size,
                              hipStream_t stream) {
    const float* inp   = (const float*)d_in[0];
    const float* wgt   = (const float*)d_in[1];
    const float* wfac  = (const float*)d_in[2];
    const float* scale = (const float*)d_in[3];
    float* out = (float*)d_out;

    sobel_direct<<<2048, 256, 0, stream>>>(inp, wgt, wfac, scale, out);
}

// Round 6
// 14.501 us; speedup vs baseline: 1.7982x; 1.2281x over previous
//
#include <hip/hip_runtime.h>

typedef float vf4 __attribute__((ext_vector_type(4)));  // native vec for nontemporal store

// One block per 64x64 image, 256 threads, no LDS staging (image fits L1).
// Thread (R = tid>>4, c = tid&15) computes output rows 4R..4R+3, cols 4c..4c+3.
// Horizontal halo comes from neighbor lanes via __shfl (width 16) instead of
// extra global loads: lane c's float4 m.w/m.x are lane c-1/c+1's halo values.
__global__ __launch_bounds__(256, 6) void sobel_v5(
    const float* __restrict__ in,      // (2048,1,64,64)
    const float* __restrict__ weight,  // (1,9)
    const float* __restrict__ wfac_p,  // (1,)
    const float* __restrict__ scale_p, // (1,1)
    float* __restrict__ out)
{
    __shared__ float smin[4], smax[4];

    const int tid = threadIdx.x;
    const int img = blockIdx.x;
    const float* __restrict__ src = in + (size_t)img * 4096;
    float* __restrict__ dst = out + (size_t)img * 4096;

    // wr = clip(weight,-1,1) * clip(wfac,1,255)
    const float wf = fminf(fmaxf(wfac_p[0], 1.0f), 255.0f);
    float wr[9];
#pragma unroll
    for (int i = 0; i < 9; ++i)
        wr[i] = fminf(fmaxf(weight[i], -1.0f), 1.0f) * wf;
    const float invscale = 1.0f / scale_p[0];

    const int c = tid & 15;   // col block: cols 4c..4c+3
    const int R = tid >> 4;   // row block: rows 4R..4R+3

    // Issue all 6 row loads up front (max ILP, clamped row addressing).
    vf4 m[6];
#pragma unroll
    for (int k = 0; k < 6; ++k) {
        const int rr = 4 * R - 1 + k;
        const int rrc = min(max(rr, 0), 63);
        m[k] = *(const vf4*)(src + rrc * 64 + 4 * c);
    }

    // Expand to 6x6 windows: horizontal halo via intra-16-lane shuffle,
    // vertical halo via row-valid mask.
    float w6[6][6];
#pragma unroll
    for (int k = 0; k < 6; ++k) {
        const int rr = 4 * R - 1 + k;
        const bool rv = (rr >= 0) & (rr < 64);
        float lft = __shfl_up(m[k].w, 1, 16);    // lane c-1's col 4c-1
        float rgt = __shfl_down(m[k].x, 1, 16);  // lane c+1's col 4c+4
        lft = (c == 0)  ? 0.0f : lft;
        rgt = (c == 15) ? 0.0f : rgt;
        w6[k][0] = rv ? lft     : 0.0f;
        w6[k][1] = rv ? m[k].x  : 0.0f;
        w6[k][2] = rv ? m[k].y  : 0.0f;
        w6[k][3] = rv ? m[k].z  : 0.0f;
        w6[k][4] = rv ? m[k].w  : 0.0f;
        w6[k][5] = rv ? rgt     : 0.0f;
    }

    // 3x3 cross-correlation with wr and wr^T, g = |gx|+|gy|.
    float g[4][4];
    float gmn = __builtin_inff(), gmx = -__builtin_inff();
#pragma unroll
    for (int i = 0; i < 4; ++i) {
#pragma unroll
        for (int j = 0; j < 4; ++j) {
            float gx = 0.0f, gy = 0.0f;
#pragma unroll
            for (int dr = 0; dr < 3; ++dr) {
#pragma unroll
                for (int dc = 0; dc < 3; ++dc) {
                    const float a = w6[i + dr][j + dc];
                    gx = fmaf(a, wr[dr * 3 + dc], gx);
                    gy = fmaf(a, wr[dc * 3 + dr], gy);
                }
            }
            const float gv = fabsf(gx) + fabsf(gy);
            g[i][j] = gv;
            gmn = fminf(gmn, gv);
            gmx = fmaxf(gmx, gv);
        }
    }

    // Per-image min/max: 64-lane butterfly, then 4 waves via LDS.
#pragma unroll
    for (int off = 32; off > 0; off >>= 1) {
        gmn = fminf(gmn, __shfl_xor(gmn, off));
        gmx = fmaxf(gmx, __shfl_xor(gmx, off));
    }
    if ((tid & 63) == 0) { smin[tid >> 6] = gmn; smax[tid >> 6] = gmx; }
    __syncthreads();
    gmn = fminf(fminf(smin[0], smin[1]), fminf(smin[2], smin[3]));
    gmx = fmaxf(fmaxf(smax[0], smax[1]), fmaxf(smax[2], smax[3]));

    const float inv = 255.0f / fmaxf(gmx - gmn, 1.0f);

    // Nontemporal float4 stores (output never re-read).
#pragma unroll
    for (int i = 0; i < 4; ++i) {
        vf4 o;
        o.x = floorf((g[i][0] - gmn) * inv) * invscale;
        o.y = floorf((g[i][1] - gmn) * inv) * invscale;
        o.z = floorf((g[i][2] - gmn) * inv) * invscale;
        o.w = floorf((g[i][3] - gmn) * inv) * invscale;
        __builtin_nontemporal_store(o, (vf4*)&dst[(4 * R + i) * 64 + 4 * c]);
    }
}

extern "C" void kernel_launch(void* const* d_in, const int* in_sizes, int n_in,
                              void* d_out, int out_size, void* d_ws, size_t ws_size,
                              hipStream_t stream) {
    const float* inp   = (const float*)d_in[0];
    const float* wgt   = (const float*)d_in[1];
    const float* wfac  = (const float*)d_in[2];
    const float* scale = (const float*)d_in[3];
    float* out = (float*)d_out;

    sobel_v5<<<2048, 256, 0, stream>>>(inp, wgt, wfac, scale, out);
}

// Round 7
// 14.452 us; speedup vs baseline: 1.8043x; 1.0034x over previous
//
#include <hip/hip_runtime.h>

typedef float vf4 __attribute__((ext_vector_type(4)));

// One block per 2 images, 256 threads, no LDS staging (images fit L1).
// Per image: thread (R = tid>>4, c = tid&15) computes rows 4R..4R+3, cols 4c..4c+3.
// Horizontal halo via __shfl within 16-lane groups; vertical halo via row mask.
// Image-2 loads are issued before image-1 compute so img1's compute/store
// overlaps img2's load latency (continuous read+write HBM streams).
__global__ __launch_bounds__(256, 4) void sobel_v6(
    const float* __restrict__ in,      // (2048,1,64,64)
    const float* __restrict__ weight,  // (1,9)
    const float* __restrict__ wfac_p,  // (1,)
    const float* __restrict__ scale_p, // (1,1)
    float* __restrict__ out)
{
    __shared__ float smin[2][4], smax[2][4];

    const int tid = threadIdx.x;
    const int img0 = blockIdx.x * 2;

    const float wf = fminf(fmaxf(wfac_p[0], 1.0f), 255.0f);
    float wr[9];
#pragma unroll
    for (int i = 0; i < 9; ++i)
        wr[i] = fminf(fmaxf(weight[i], -1.0f), 1.0f) * wf;
    const float invscale = 1.0f / scale_p[0];

    const int c = tid & 15;
    const int R = tid >> 4;
    const int wv = tid >> 6;

    const float* __restrict__ src0 = in + (size_t)img0 * 4096;
    const float* __restrict__ src1 = src0 + 4096;

    // ---- img1 loads ----
    vf4 m[6];
#pragma unroll
    for (int k = 0; k < 6; ++k) {
        const int rr = 4 * R - 1 + k;
        const int rrc = min(max(rr, 0), 63);
        m[k] = *(const vf4*)(src0 + rrc * 64 + 4 * c);
    }

    // ---- img1 window expansion (frees m) ----
    float w6[6][6];
#pragma unroll
    for (int k = 0; k < 6; ++k) {
        const int rr = 4 * R - 1 + k;
        const bool rv = (rr >= 0) & (rr < 64);
        float lft = __shfl_up(m[k].w, 1, 16);
        float rgt = __shfl_down(m[k].x, 1, 16);
        lft = (c == 0)  ? 0.0f : lft;
        rgt = (c == 15) ? 0.0f : rgt;
        w6[k][0] = rv ? lft    : 0.0f;
        w6[k][1] = rv ? m[k].x : 0.0f;
        w6[k][2] = rv ? m[k].y : 0.0f;
        w6[k][3] = rv ? m[k].z : 0.0f;
        w6[k][4] = rv ? m[k].w : 0.0f;
        w6[k][5] = rv ? rgt    : 0.0f;
    }

    // ---- issue img2 loads now; latency hides under img1 compute/reduce/store ----
    vf4 m2[6];
#pragma unroll
    for (int k = 0; k < 6; ++k) {
        const int rr = 4 * R - 1 + k;
        const int rrc = min(max(rr, 0), 63);
        m2[k] = *(const vf4*)(src1 + rrc * 64 + 4 * c);
    }

    // ---- img1 conv ----
    float g[4][4];
    float gmn = __builtin_inff(), gmx = -__builtin_inff();
#pragma unroll
    for (int i = 0; i < 4; ++i) {
#pragma unroll
        for (int j = 0; j < 4; ++j) {
            float gx = 0.0f, gy = 0.0f;
#pragma unroll
            for (int dr = 0; dr < 3; ++dr) {
#pragma unroll
                for (int dc = 0; dc < 3; ++dc) {
                    const float a = w6[i + dr][j + dc];
                    gx = fmaf(a, wr[dr * 3 + dc], gx);
                    gy = fmaf(a, wr[dc * 3 + dr], gy);
                }
            }
            const float gv = fabsf(gx) + fabsf(gy);
            g[i][j] = gv;
            gmn = fminf(gmn, gv);
            gmx = fmaxf(gmx, gv);
        }
    }

    // ---- img1 reduce ----
#pragma unroll
    for (int off = 32; off > 0; off >>= 1) {
        gmn = fminf(gmn, __shfl_xor(gmn, off));
        gmx = fmaxf(gmx, __shfl_xor(gmx, off));
    }
    if ((tid & 63) == 0) { smin[0][wv] = gmn; smax[0][wv] = gmx; }
    __syncthreads();
    gmn = fminf(fminf(smin[0][0], smin[0][1]), fminf(smin[0][2], smin[0][3]));
    gmx = fmaxf(fmaxf(smax[0][0], smax[0][1]), fmaxf(smax[0][2], smax[0][3]));

    // ---- img1 store ----
    {
        const float inv = 255.0f / fmaxf(gmx - gmn, 1.0f);
        float* __restrict__ dst = out + (size_t)img0 * 4096;
#pragma unroll
        for (int i = 0; i < 4; ++i) {
            vf4 o;
            o.x = floorf((g[i][0] - gmn) * inv) * invscale;
            o.y = floorf((g[i][1] - gmn) * inv) * invscale;
            o.z = floorf((g[i][2] - gmn) * inv) * invscale;
            o.w = floorf((g[i][3] - gmn) * inv) * invscale;
            __builtin_nontemporal_store(o, (vf4*)&dst[(4 * R + i) * 64 + 4 * c]);
        }
    }

    // ---- img2 window expansion ----
#pragma unroll
    for (int k = 0; k < 6; ++k) {
        const int rr = 4 * R - 1 + k;
        const bool rv = (rr >= 0) & (rr < 64);
        float lft = __shfl_up(m2[k].w, 1, 16);
        float rgt = __shfl_down(m2[k].x, 1, 16);
        lft = (c == 0)  ? 0.0f : lft;
        rgt = (c == 15) ? 0.0f : rgt;
        w6[k][0] = rv ? lft     : 0.0f;
        w6[k][1] = rv ? m2[k].x : 0.0f;
        w6[k][2] = rv ? m2[k].y : 0.0f;
        w6[k][3] = rv ? m2[k].z : 0.0f;
        w6[k][4] = rv ? m2[k].w : 0.0f;
        w6[k][5] = rv ? rgt     : 0.0f;
    }

    // ---- img2 conv ----
    gmn = __builtin_inff(); gmx = -__builtin_inff();
#pragma unroll
    for (int i = 0; i < 4; ++i) {
#pragma unroll
        for (int j = 0; j < 4; ++j) {
            float gx = 0.0f, gy = 0.0f;
#pragma unroll
            for (int dr = 0; dr < 3; ++dr) {
#pragma unroll
                for (int dc = 0; dc < 3; ++dc) {
                    const float a = w6[i + dr][j + dc];
                    gx = fmaf(a, wr[dr * 3 + dc], gx);
                    gy = fmaf(a, wr[dc * 3 + dr], gy);
                }
            }
            const float gv = fabsf(gx) + fabsf(gy);
            g[i][j] = gv;
            gmn = fminf(gmn, gv);
            gmx = fmaxf(gmx, gv);
        }
    }

    // ---- img2 reduce ----
#pragma unroll
    for (int off = 32; off > 0; off >>= 1) {
        gmn = fminf(gmn, __shfl_xor(gmn, off));
        gmx = fmaxf(gmx, __shfl_xor(gmx, off));
    }
    if ((tid & 63) == 0) { smin[1][wv] = gmn; smax[1][wv] = gmx; }
    __syncthreads();
    gmn = fminf(fminf(smin[1][0], smin[1][1]), fminf(smin[1][2], smin[1][3]));
    gmx = fmaxf(fmaxf(smax[1][0], smax[1][1]), fmaxf(smax[1][2], smax[1][3]));

    // ---- img2 store ----
    {
        const float inv = 255.0f / fmaxf(gmx - gmn, 1.0f);
        float* __restrict__ dst = out + (size_t)(img0 + 1) * 4096;
#pragma unroll
        for (int i = 0; i < 4; ++i) {
            vf4 o;
            o.x = floorf((g[i][0] - gmn) * inv) * invscale;
            o.y = floorf((g[i][1] - gmn) * inv) * invscale;
            o.z = floorf((g[i][2] - gmn) * inv) * invscale;
            o.w = floorf((g[i][3] - gmn) * inv) * invscale;
            __builtin_nontemporal_store(o, (vf4*)&dst[(4 * R + i) * 64 + 4 * c]);
        }
    }
}

extern "C" void kernel_launch(void* const* d_in, const int* in_sizes, int n_in,
                              void* d_out, int out_size, void* d_ws, size_t ws_size,
                              hipStream_t stream) {
    const float* inp   = (const float*)d_in[0];
    const float* wgt   = (const float*)d_in[1];
    const float* wfac  = (const float*)d_in[2];
    const float* scale = (const float*)d_in[3];
    float* out = (float*)d_out;

    sobel_v6<<<1024, 256, 0, stream>>>(inp, wgt, wfac, scale, out);
}

// Round 8
// 14.062 us; speedup vs baseline: 1.8544x; 1.0278x over previous
//
#include <hip/hip_runtime.h>

typedef float vf4 __attribute__((ext_vector_type(4)));

// Async global->LDS, 16B per lane, wave-uniform LDS base (HW: base + lane*16).
__device__ __forceinline__ void gload_lds16(const void* g, void* l) {
    __builtin_amdgcn_global_load_lds(
        (const __attribute__((address_space(1))) void*)g,
        (__attribute__((address_space(3))) void*)l,
        16, 0, 0);
}

// One block per 64x64 image, 256 threads.
// Stage: whole image (16 KB) via global_load_lds -> 128 KB outstanding reads/CU
// (8 blocks/CU), saturating the HBM read stream without VGPR cost.
// Compute: thread (R=tid>>4, c=tid&15) does rows 4R..4R+3, cols 4c..4c+3;
// ds_read_b128 pattern is conflict-free (banks c*4 mod 32, 8 lanes/4-bank group);
// horizontal halo via __shfl within 16-lane groups, vertical via row mask.
__global__ __launch_bounds__(256) void sobel_v7(
    const float* __restrict__ in,      // (2048,1,64,64)
    const float* __restrict__ weight,  // (1,9)
    const float* __restrict__ wfac_p,  // (1,)
    const float* __restrict__ scale_p, // (1,1)
    float* __restrict__ out)
{
    __shared__ __align__(16) float img[4096];   // 16 KB, linear row-major
    __shared__ float smin[4], smax[4];

    const int tid  = threadIdx.x;
    const int lane = tid & 63;
    const int wv   = tid >> 6;
    const float* __restrict__ src = in + (size_t)blockIdx.x * 4096;
    float* __restrict__ dst = out + (size_t)blockIdx.x * 4096;

    // Issue the whole image as direct-to-LDS loads: 4 calls/wave x 1 KB.
#pragma unroll
    for (int k = 0; k < 4; ++k) {
        const int ci = wv * 4 + k;                      // 1KB chunk id, 0..15
        gload_lds16(src + ci * 256 + lane * 4, &img[ci * 256]);
    }

    // Uniform prep overlaps the load latency.
    const float wf = fminf(fmaxf(wfac_p[0], 1.0f), 255.0f);
    float wr[9];
#pragma unroll
    for (int i = 0; i < 9; ++i)
        wr[i] = fminf(fmaxf(weight[i], -1.0f), 1.0f) * wf;
    const float invscale = 1.0f / scale_p[0];

    __syncthreads();   // compiler emits s_waitcnt vmcnt(0) before s_barrier

    const int c = tid & 15;   // col block: cols 4c..4c+3
    const int R = tid >> 4;   // row block: rows 4R..4R+3

    // 6 conflict-free ds_read_b128 (rows clamped; mask zeroes halo rows).
    vf4 m[6];
#pragma unroll
    for (int k = 0; k < 6; ++k) {
        const int rr = 4 * R - 1 + k;
        const int rrc = min(max(rr, 0), 63);
        m[k] = *(const vf4*)&img[rrc * 64 + 4 * c];
    }

    float w6[6][6];
#pragma unroll
    for (int k = 0; k < 6; ++k) {
        const int rr = 4 * R - 1 + k;
        const bool rv = (rr >= 0) & (rr < 64);
        float lft = __shfl_up(m[k].w, 1, 16);    // lane c-1's col 4c-1
        float rgt = __shfl_down(m[k].x, 1, 16);  // lane c+1's col 4c+4
        lft = (c == 0)  ? 0.0f : lft;
        rgt = (c == 15) ? 0.0f : rgt;
        w6[k][0] = rv ? lft    : 0.0f;
        w6[k][1] = rv ? m[k].x : 0.0f;
        w6[k][2] = rv ? m[k].y : 0.0f;
        w6[k][3] = rv ? m[k].z : 0.0f;
        w6[k][4] = rv ? m[k].w : 0.0f;
        w6[k][5] = rv ? rgt    : 0.0f;
    }

    // 3x3 cross-correlation with wr and wr^T, g = |gx|+|gy|.
    float g[4][4];
    float gmn = __builtin_inff(), gmx = -__builtin_inff();
#pragma unroll
    for (int i = 0; i < 4; ++i) {
#pragma unroll
        for (int j = 0; j < 4; ++j) {
            float gx = 0.0f, gy = 0.0f;
#pragma unroll
            for (int dr = 0; dr < 3; ++dr) {
#pragma unroll
                for (int dc = 0; dc < 3; ++dc) {
                    const float a = w6[i + dr][j + dc];
                    gx = fmaf(a, wr[dr * 3 + dc], gx);
                    gy = fmaf(a, wr[dc * 3 + dr], gy);
                }
            }
            const float gv = fabsf(gx) + fabsf(gy);
            g[i][j] = gv;
            gmn = fminf(gmn, gv);
            gmx = fmaxf(gmx, gv);
        }
    }

    // Per-image min/max: 64-lane butterfly, then 4 waves via LDS.
#pragma unroll
    for (int off = 32; off > 0; off >>= 1) {
        gmn = fminf(gmn, __shfl_xor(gmn, off));
        gmx = fmaxf(gmx, __shfl_xor(gmx, off));
    }
    if (lane == 0) { smin[wv] = gmn; smax[wv] = gmx; }
    __syncthreads();
    gmn = fminf(fminf(smin[0], smin[1]), fminf(smin[2], smin[3]));
    gmx = fmaxf(fmaxf(smax[0], smax[1]), fmaxf(smax[2], smax[3]));

    const float inv = 255.0f / fmaxf(gmx - gmn, 1.0f);

#pragma unroll
    for (int i = 0; i < 4; ++i) {
        vf4 o;
        o.x = floorf((g[i][0] - gmn) * inv) * invscale;
        o.y = floorf((g[i][1] - gmn) * inv) * invscale;
        o.z = floorf((g[i][2] - gmn) * inv) * invscale;
        o.w = floorf((g[i][3] - gmn) * inv) * invscale;
        __builtin_nontemporal_store(o, (vf4*)&dst[(4 * R + i) * 64 + 4 * c]);
    }
}

extern "C" void kernel_launch(void* const* d_in, const int* in_sizes, int n_in,
                              void* d_out, int out_size, void* d_ws, size_t ws_size,
                              hipStream_t stream) {
    const float* inp   = (const float*)d_in[0];
    const float* wgt   = (const float*)d_in[1];
    const float* wfac  = (const float*)d_in[2];
    const float* scale = (const float*)d_in[3];
    float* out = (float*)d_out;

    sobel_v7<<<2048, 256, 0, stream>>>(inp, wgt, wfac, scale, out);
}